// Round 1
// baseline (1177.521 us; speedup 1.0000x reference)
//
#include <hip/hip_runtime.h>

#define N_NODES   100000
#define N_EDGES   1600000
#define DIM       128
#define OUT_CH    10
#define NUM_GRAPHS 128
#define BN_EPS    1e-5f

// ============================ CSR build ============================

__global__ void k_count(const int* __restrict__ dst, int* __restrict__ cnt) {
    int e = blockIdx.x * 256 + threadIdx.x;
    if (e < N_EDGES) atomicAdd(&cnt[dst[e]], 1);
}

// 1024 elements per block, 98 blocks. Writes intra-block exclusive prefix.
__global__ void k_scanA(const int* __restrict__ cnt, int* __restrict__ outv,
                        int* __restrict__ bsum) {
    __shared__ int sh[256];
    int t = threadIdx.x;
    int base = blockIdx.x * 1024 + t * 4;
    int v0=0,v1=0,v2=0,v3=0;
    if (base+0 < N_NODES) v0 = cnt[base+0];
    if (base+1 < N_NODES) v1 = cnt[base+1];
    if (base+2 < N_NODES) v2 = cnt[base+2];
    if (base+3 < N_NODES) v3 = cnt[base+3];
    int s = v0+v1+v2+v3;
    sh[t] = s; __syncthreads();
    for (int off = 1; off < 256; off <<= 1) {
        int tmp = (t >= off) ? sh[t-off] : 0;
        __syncthreads();
        sh[t] += tmp;
        __syncthreads();
    }
    int excl = sh[t] - s;
    if (t == 255) bsum[blockIdx.x] = sh[255];
    int run = excl;
    if (base+0 < N_NODES) { outv[base+0] = run; run += v0; }
    if (base+1 < N_NODES) { outv[base+1] = run; run += v1; }
    if (base+2 < N_NODES) { outv[base+2] = run; run += v2; }
    if (base+3 < N_NODES) { outv[base+3] = run; run += v3; }
}

__global__ void k_scanB(int* __restrict__ bsum, int* __restrict__ row_ptr) {
    if (threadIdx.x == 0 && blockIdx.x == 0) {
        int run = 0;
        for (int i = 0; i < 98; ++i) { int v = bsum[i]; bsum[i] = run; run += v; }
        row_ptr[N_NODES] = run;   // == N_EDGES
    }
}

__global__ void k_scanC(int* __restrict__ row_ptr, const int* __restrict__ bsum,
                        int* __restrict__ cursor) {
    int i = blockIdx.x * 256 + threadIdx.x;
    if (i < N_NODES) {
        int v = row_ptr[i] + bsum[i >> 10];
        row_ptr[i] = v;
        cursor[i]  = v;
    }
}

__global__ void k_fill(const int* __restrict__ src, const int* __restrict__ dst,
                       int* __restrict__ cursor, int* __restrict__ col) {
    int e = blockIdx.x * 256 + threadIdx.x;
    if (e < N_EDGES) {
        int d = dst[e];
        int p = atomicAdd(&cursor[d], 1);
        col[p] = src[e];
    }
}

// ============================ Aggregation ============================
// out[i] = in[i] + sum_{j in N(i)} in[j].  One wave per node, float2 per lane.
__global__ void k_agg(const float* __restrict__ X, float* __restrict__ Out,
                      const int* __restrict__ row_ptr, const int* __restrict__ col) {
    int wid  = (blockIdx.x * blockDim.x + threadIdx.x) >> 6;
    int lane = threadIdx.x & 63;
    if (wid >= N_NODES) return;
    const float2* x2 = (const float2*)X;
    float2 acc = x2[(size_t)wid * 64 + lane];
    int s = row_ptr[wid], e = row_ptr[wid + 1];
    for (int p = s; p < e; ++p) {
        int nb = col[p];
        float2 v = x2[(size_t)nb * 64 + lane];
        acc.x += v.x; acc.y += v.y;
    }
    ((float2*)Out)[(size_t)wid * 64 + lane] = acc;
}

// ============================ GEMM [N,128] @ [128,128] ============================
// Tile: 64 rows x 64 cols per block, 256 threads, each thread 4x4 outputs.
// BN_LOAD: y = relu(in*scale[k]+shift[k]) applied while staging input tile.
// STATS:   accumulate per-channel sum/sumsq of the (bias-added) output.
// RELU_ST: relu on store.
template<bool BN_LOAD, bool STATS, bool RELU_ST>
__global__ __launch_bounds__(256)
void k_gemm(const float* __restrict__ In, float* __restrict__ Out,
            const float* __restrict__ W, const float* __restrict__ bias,
            const float* __restrict__ scale, const float* __restrict__ shift,
            float* __restrict__ stat_sum, float* __restrict__ stat_sq) {
    __shared__ float S[64][132];    // input rows (k-major), +4 pad
    __shared__ float Wt[64][132];   // W transposed: Wt[c_local][k], +4 pad
    __shared__ float s_sum[64], s_sq[64];

    int t  = threadIdx.x;
    int r0 = blockIdx.y * 64;
    int c0 = blockIdx.x * 64;

    if (STATS && t < 64) { s_sum[t] = 0.f; s_sq[t] = 0.f; }

    // stage input tile: 64 rows x 128 k = 2048 float4s
    #pragma unroll
    for (int u = 0; u < 8; ++u) {
        int fi  = u * 256 + t;
        int row = fi >> 5;
        int kq  = fi & 31;
        float4 v = make_float4(0.f, 0.f, 0.f, 0.f);
        int gr = r0 + row;
        if (gr < N_NODES) v = *(const float4*)(In + (size_t)gr * 128 + kq * 4);
        if (BN_LOAD) {
            int k = kq * 4;
            v.x = fmaxf(v.x * scale[k+0] + shift[k+0], 0.f);
            v.y = fmaxf(v.y * scale[k+1] + shift[k+1], 0.f);
            v.z = fmaxf(v.z * scale[k+2] + shift[k+2], 0.f);
            v.w = fmaxf(v.w * scale[k+3] + shift[k+3], 0.f);
        }
        *(float4*)&S[row][kq * 4] = v;
    }
    // stage W tile transposed: 128 k x 16 col-quads = 2048 float4s
    #pragma unroll
    for (int u = 0; u < 8; ++u) {
        int fi = u * 256 + t;
        int k  = fi >> 4;
        int cq = fi & 15;
        float4 wv = *(const float4*)(W + (size_t)k * 128 + c0 + cq * 4);
        Wt[cq*4+0][k] = wv.x; Wt[cq*4+1][k] = wv.y;
        Wt[cq*4+2][k] = wv.z; Wt[cq*4+3][k] = wv.w;
    }
    __syncthreads();

    int rl = (t >> 4) * 4;   // local row base
    int cl = (t & 15) * 4;   // local col base
    float acc[4][4] = {};
    #pragma unroll 8
    for (int kq = 0; kq < 32; ++kq) {
        float4 a0 = *(const float4*)&S[rl+0][kq*4];
        float4 a1 = *(const float4*)&S[rl+1][kq*4];
        float4 a2 = *(const float4*)&S[rl+2][kq*4];
        float4 a3 = *(const float4*)&S[rl+3][kq*4];
        float4 b0 = *(const float4*)&Wt[cl+0][kq*4];
        float4 b1 = *(const float4*)&Wt[cl+1][kq*4];
        float4 b2 = *(const float4*)&Wt[cl+2][kq*4];
        float4 b3 = *(const float4*)&Wt[cl+3][kq*4];
        acc[0][0] += a0.x*b0.x + a0.y*b0.y + a0.z*b0.z + a0.w*b0.w;
        acc[0][1] += a0.x*b1.x + a0.y*b1.y + a0.z*b1.z + a0.w*b1.w;
        acc[0][2] += a0.x*b2.x + a0.y*b2.y + a0.z*b2.z + a0.w*b2.w;
        acc[0][3] += a0.x*b3.x + a0.y*b3.y + a0.z*b3.z + a0.w*b3.w;
        acc[1][0] += a1.x*b0.x + a1.y*b0.y + a1.z*b0.z + a1.w*b0.w;
        acc[1][1] += a1.x*b1.x + a1.y*b1.y + a1.z*b1.z + a1.w*b1.w;
        acc[1][2] += a1.x*b2.x + a1.y*b2.y + a1.z*b2.z + a1.w*b2.w;
        acc[1][3] += a1.x*b3.x + a1.y*b3.y + a1.z*b3.z + a1.w*b3.w;
        acc[2][0] += a2.x*b0.x + a2.y*b0.y + a2.z*b0.z + a2.w*b0.w;
        acc[2][1] += a2.x*b1.x + a2.y*b1.y + a2.z*b1.z + a2.w*b1.w;
        acc[2][2] += a2.x*b2.x + a2.y*b2.y + a2.z*b2.z + a2.w*b2.w;
        acc[2][3] += a2.x*b3.x + a2.y*b3.y + a2.z*b3.z + a2.w*b3.w;
        acc[3][0] += a3.x*b0.x + a3.y*b0.y + a3.z*b0.z + a3.w*b0.w;
        acc[3][1] += a3.x*b1.x + a3.y*b1.y + a3.z*b1.z + a3.w*b1.w;
        acc[3][2] += a3.x*b2.x + a3.y*b2.y + a3.z*b2.z + a3.w*b2.w;
        acc[3][3] += a3.x*b3.x + a3.y*b3.y + a3.z*b3.z + a3.w*b3.w;
    }

    float4 bb4 = *(const float4*)(bias + c0 + cl);
    float bv[4] = { bb4.x, bb4.y, bb4.z, bb4.w };
    float lsum[4] = {0,0,0,0}, lsq[4] = {0,0,0,0};
    #pragma unroll
    for (int i = 0; i < 4; ++i) {
        int gr = r0 + rl + i;
        float o[4];
        #pragma unroll
        for (int j = 0; j < 4; ++j) {
            float v = acc[i][j] + bv[j];
            if (RELU_ST) v = fmaxf(v, 0.f);
            o[j] = v;
        }
        if (gr < N_NODES) {
            *(float4*)(Out + (size_t)gr * 128 + c0 + cl) = make_float4(o[0], o[1], o[2], o[3]);
            if (STATS) {
                #pragma unroll
                for (int j = 0; j < 4; ++j) { lsum[j] += o[j]; lsq[j] += o[j]*o[j]; }
            }
        }
    }
    if (STATS) {
        #pragma unroll
        for (int j = 0; j < 4; ++j) {
            atomicAdd(&s_sum[cl + j], lsum[j]);
            atomicAdd(&s_sq [cl + j], lsq [j]);
        }
        __syncthreads();
        if (t < 64) {
            atomicAdd(&stat_sum[c0 + t], s_sum[t]);
            atomicAdd(&stat_sq [c0 + t], s_sq [t]);
        }
    }
}

__global__ void k_bnfin(const float* __restrict__ sum, const float* __restrict__ sq,
                        const float* __restrict__ gamma, const float* __restrict__ beta,
                        float* __restrict__ scale, float* __restrict__ shift) {
    int c = threadIdx.x;
    if (c < DIM) {
        float m   = sum[c] * (1.0f / N_NODES);
        float var = sq[c] * (1.0f / N_NODES) - m * m;
        float inv = rsqrtf(var + BN_EPS);
        float sc  = gamma[c] * inv;
        scale[c] = sc;
        shift[c] = beta[c] - m * sc;
    }
}

// ============================ Pooling (batch is sorted) ============================
#define POOL_BLOCKS 512
#define POOL_CHUNK  196
__global__ void k_pool(const float* __restrict__ h, const int* __restrict__ batch,
                       float* __restrict__ pooled) {
    int c  = threadIdx.x;                 // 128 threads = 128 channels
    int n0 = blockIdx.x * POOL_CHUNK;
    if (n0 >= N_NODES) return;
    int n1 = min(n0 + POOL_CHUNK, N_NODES);
    int g = batch[n0];
    float acc = 0.f;
    for (int i = n0; i < n1; ++i) {
        int gi = batch[i];
        if (gi != g) { atomicAdd(&pooled[g * DIM + c], acc); acc = 0.f; g = gi; }
        acc += h[(size_t)i * DIM + c];
    }
    atomicAdd(&pooled[g * DIM + c], acc);
}

// ============================ Readout ============================
__global__ void k_readout1(const float* __restrict__ pooled, const float* __restrict__ W,
                           const float* __restrict__ b, float* __restrict__ r1) {
    int idx = blockIdx.x * 256 + threadIdx.x;      // 16384
    int g = idx >> 7, c = idx & 127;
    float s = b[c];
    const float* p = pooled + g * DIM;
    #pragma unroll 8
    for (int k = 0; k < DIM; ++k) s += p[k] * W[k * DIM + c];
    r1[idx] = fmaxf(s, 0.f);
}

__global__ void k_readout2(const float* __restrict__ r1, const float* __restrict__ W,
                           const float* __restrict__ b, float* __restrict__ out) {
    int idx = blockIdx.x * 256 + threadIdx.x;      // 1280
    if (idx >= NUM_GRAPHS * OUT_CH) return;
    int g = idx / OUT_CH, c = idx % OUT_CH;
    float s = b[c];
    const float* r = r1 + g * DIM;
    #pragma unroll 8
    for (int k = 0; k < DIM; ++k) s += r[k] * W[k * OUT_CH + c];
    out[idx] = s;
}

// ============================ Launch ============================
extern "C" void kernel_launch(void* const* d_in, const int* in_sizes, int n_in,
                              void* d_out, int out_size, void* d_ws, size_t ws_size,
                              hipStream_t stream) {
    const float* x   = (const float*)d_in[0];
    const int*   ei  = (const int*)d_in[1];
    const int*   bat = (const int*)d_in[2];
    const float* W1a = (const float*)d_in[3];
    const float* b1a = (const float*)d_in[4];
    const float* ga  = (const float*)d_in[5];
    const float* ba  = (const float*)d_in[6];
    const float* W2a = (const float*)d_in[7];
    const float* b2a = (const float*)d_in[8];
    const float* W1b = (const float*)d_in[9];
    const float* b1b = (const float*)d_in[10];
    const float* gb  = (const float*)d_in[11];
    const float* bbta= (const float*)d_in[12];
    const float* W2b = (const float*)d_in[13];
    const float* b2b = (const float*)d_in[14];
    const float* Wl1 = (const float*)d_in[15];
    const float* bl1 = (const float*)d_in[16];
    const float* Wl2 = (const float*)d_in[17];
    const float* bl2 = (const float*)d_in[18];
    float* out = (float*)d_out;

    const int* src = ei;
    const int* dst = ei + N_EDGES;

    char* w = (char*)d_ws;
    size_t off = 0;
    auto alloc = [&](size_t bytes) -> char* {
        char* p = w + off; off += (bytes + 255) & ~(size_t)255; return p;
    };
    float* buf0    = (float*)alloc((size_t)N_NODES * DIM * 4);
    float* buf1    = (float*)alloc((size_t)N_NODES * DIM * 4);
    int*   row_ptr = (int*)  alloc((size_t)(N_NODES + 1) * 4);
    int*   cursor  = (int*)  alloc((size_t)N_NODES * 4);
    int*   col     = (int*)  alloc((size_t)N_EDGES * 4);
    int*   bsum    = (int*)  alloc(98 * 4);
    float* ssum    = (float*)alloc(DIM * 4);
    float* ssq     = (float*)alloc(DIM * 4);
    float* scale   = (float*)alloc(DIM * 4);
    float* shift   = (float*)alloc(DIM * 4);
    float* pooled  = (float*)alloc((size_t)NUM_GRAPHS * DIM * 4);
    float* r1      = (float*)alloc((size_t)NUM_GRAPHS * DIM * 4);

    hipMemsetAsync(cursor, 0, (size_t)N_NODES * 4, stream);
    hipMemsetAsync(ssum,   0, DIM * 4, stream);
    hipMemsetAsync(ssq,    0, DIM * 4, stream);
    hipMemsetAsync(pooled, 0, (size_t)NUM_GRAPHS * DIM * 4, stream);

    // CSR build (by dst, col = src)
    k_count<<<N_EDGES / 256, 256, 0, stream>>>(dst, cursor);
    k_scanA<<<98, 256, 0, stream>>>(cursor, row_ptr, bsum);
    k_scanB<<<1, 64, 0, stream>>>(bsum, row_ptr);
    k_scanC<<<(N_NODES + 255) / 256, 256, 0, stream>>>(row_ptr, bsum, cursor);
    k_fill<<<N_EDGES / 256, 256, 0, stream>>>(src, dst, cursor, col);

    dim3 ggrid(2, (N_NODES + 63) / 64);
    int agg_blocks = (N_NODES * 64) / 256;

    // conv1
    k_agg<<<agg_blocks, 256, 0, stream>>>(x, buf0, row_ptr, col);
    k_gemm<false, true, false><<<ggrid, 256, 0, stream>>>(buf0, buf1, W1a, b1a,
                                                          nullptr, nullptr, ssum, ssq);
    k_bnfin<<<1, 128, 0, stream>>>(ssum, ssq, ga, ba, scale, shift);
    k_gemm<true, false, true><<<ggrid, 256, 0, stream>>>(buf1, buf0, W2a, b2a,
                                                         scale, shift, nullptr, nullptr);
    // conv2
    hipMemsetAsync(ssum, 0, DIM * 4, stream);
    hipMemsetAsync(ssq,  0, DIM * 4, stream);
    k_agg<<<agg_blocks, 256, 0, stream>>>(buf0, buf1, row_ptr, col);
    k_gemm<false, true, false><<<ggrid, 256, 0, stream>>>(buf1, buf0, W1b, b1b,
                                                          nullptr, nullptr, ssum, ssq);
    k_bnfin<<<1, 128, 0, stream>>>(ssum, ssq, gb, bbta, scale, shift);
    k_gemm<true, false, true><<<ggrid, 256, 0, stream>>>(buf0, buf1, W2b, b2b,
                                                         scale, shift, nullptr, nullptr);
    // readout
    k_pool<<<POOL_BLOCKS, 128, 0, stream>>>(buf1, bat, pooled);
    k_readout1<<<(NUM_GRAPHS * DIM) / 256, 256, 0, stream>>>(pooled, Wl1, bl1, r1);
    k_readout2<<<(NUM_GRAPHS * OUT_CH + 255) / 256, 256, 0, stream>>>(r1, Wl2, bl2, out);
}

// Round 2
// 779.479 us; speedup vs baseline: 1.5107x; 1.5107x over previous
//
#include <hip/hip_runtime.h>

#define N_NODES    100000
#define N_EDGES    1600000
#define DIM        128
#define OUT_CH     10
#define NUM_GRAPHS 128
#define BN_EPS     1e-5f

typedef __attribute__((ext_vector_type(8))) short short8;
typedef __attribute__((ext_vector_type(4))) float floatx4;

__device__ inline float bf2f(unsigned short u) {
    union { unsigned i; float f; } v; v.i = (unsigned)u << 16; return v.f;
}
__device__ inline unsigned short f2bf(float f) {
    union { float f; unsigned i; } v; v.f = f;
    unsigned r = (v.i + 0x7fffu + ((v.i >> 16) & 1u)) >> 16;
    return (unsigned short)r;
}

// ============================ CSR build ============================

__global__ void k_count(const int* __restrict__ dst, int* __restrict__ cnt) {
    int e = blockIdx.x * 256 + threadIdx.x;
    if (e < N_EDGES) atomicAdd(&cnt[dst[e]], 1);
}

__global__ void k_scanA(const int* __restrict__ cnt, int* __restrict__ outv,
                        int* __restrict__ bsum) {
    __shared__ int sh[256];
    int t = threadIdx.x;
    int base = blockIdx.x * 1024 + t * 4;
    int v0=0,v1=0,v2=0,v3=0;
    if (base+0 < N_NODES) v0 = cnt[base+0];
    if (base+1 < N_NODES) v1 = cnt[base+1];
    if (base+2 < N_NODES) v2 = cnt[base+2];
    if (base+3 < N_NODES) v3 = cnt[base+3];
    int s = v0+v1+v2+v3;
    sh[t] = s; __syncthreads();
    for (int off = 1; off < 256; off <<= 1) {
        int tmp = (t >= off) ? sh[t-off] : 0;
        __syncthreads();
        sh[t] += tmp;
        __syncthreads();
    }
    int excl = sh[t] - s;
    if (t == 255) bsum[blockIdx.x] = sh[255];
    int run = excl;
    if (base+0 < N_NODES) { outv[base+0] = run; run += v0; }
    if (base+1 < N_NODES) { outv[base+1] = run; run += v1; }
    if (base+2 < N_NODES) { outv[base+2] = run; run += v2; }
    if (base+3 < N_NODES) { outv[base+3] = run; run += v3; }
}

__global__ void k_scanB(int* __restrict__ bsum, int* __restrict__ row_ptr) {
    if (threadIdx.x == 0 && blockIdx.x == 0) {
        int run = 0;
        for (int i = 0; i < 98; ++i) { int v = bsum[i]; bsum[i] = run; run += v; }
        row_ptr[N_NODES] = run;
    }
}

__global__ void k_scanC(int* __restrict__ row_ptr, const int* __restrict__ bsum,
                        int* __restrict__ cursor) {
    int i = blockIdx.x * 256 + threadIdx.x;
    if (i < N_NODES) {
        int v = row_ptr[i] + bsum[i >> 10];
        row_ptr[i] = v;
        cursor[i]  = v;
    }
}

__global__ void k_fill(const int* __restrict__ src, const int* __restrict__ dst,
                       int* __restrict__ cursor, int* __restrict__ col) {
    int e = blockIdx.x * 256 + threadIdx.x;
    if (e < N_EDGES) {
        int d = dst[e];
        int p = atomicAdd(&cursor[d], 1);
        col[p] = src[e];
    }
}

// ============================ dtype prep ============================

__global__ void k_cvt_x(const float* __restrict__ x, unsigned short* __restrict__ xb) {
    int idx = blockIdx.x * 256 + threadIdx.x;      // 3.2M float4s
    float4 v = ((const float4*)x)[idx];
    ushort4 o;
    o.x = f2bf(v.x); o.y = f2bf(v.y); o.z = f2bf(v.z); o.w = f2bf(v.w);
    ((ushort4*)xb)[idx] = o;
}

// W[k][n] fp32 -> Wt[n][k] bf16, 4 matrices (blockIdx.y selects)
__global__ void k_prep_w(const float* __restrict__ W0, const float* __restrict__ W1,
                         const float* __restrict__ W2, const float* __restrict__ W3,
                         unsigned short* __restrict__ Wt) {
    const float* Ws[4] = {W0, W1, W2, W3};
    const float* W = Ws[blockIdx.y];
    unsigned short* o = Wt + blockIdx.y * (DIM * DIM);
    int idx = blockIdx.x * 256 + threadIdx.x;      // 0..16383
    int n = idx >> 7, k = idx & 127;
    o[idx] = f2bf(W[k * DIM + n]);
}

// ============================ Aggregation (bf16) ============================
// out[i] = in[i] + sum_{j in N(i)} in[j]. One wave per node; each half-wave
// covers the full 128-ch row (32 lanes x ushort4); 2 edges per iteration.
__global__ void k_agg(const unsigned short* __restrict__ X,
                      unsigned short* __restrict__ Out,
                      const int* __restrict__ row_ptr, const int* __restrict__ col) {
    int wid = (blockIdx.x * 256 + threadIdx.x) >> 6;
    if (wid >= N_NODES) return;
    int lane = threadIdx.x & 63;
    int half = lane >> 5, m = lane & 31;

    float a0 = 0.f, a1 = 0.f, a2 = 0.f, a3 = 0.f;
    if (half == 0) {
        ushort4 sv = *(const ushort4*)(X + (size_t)wid * 128 + m * 4);
        a0 = bf2f(sv.x); a1 = bf2f(sv.y); a2 = bf2f(sv.z); a3 = bf2f(sv.w);
    }
    int s = row_ptr[wid], e = row_ptr[wid + 1];
    for (int p = s + half; p < e; p += 2) {
        int nb = col[p];
        ushort4 v = *(const ushort4*)(X + (size_t)nb * 128 + m * 4);
        a0 += bf2f(v.x); a1 += bf2f(v.y); a2 += bf2f(v.z); a3 += bf2f(v.w);
    }
    a0 += __shfl_xor(a0, 32);
    a1 += __shfl_xor(a1, 32);
    a2 += __shfl_xor(a2, 32);
    a3 += __shfl_xor(a3, 32);
    if (half == 0) {
        ushort4 o;
        o.x = f2bf(a0); o.y = f2bf(a1); o.z = f2bf(a2); o.w = f2bf(a3);
        *(ushort4*)(Out + (size_t)wid * 128 + m * 4) = o;
    }
}

// ============================ MFMA GEMM [N,128] @ [128,128] ============================
// Block: 256 threads (4 waves), tile 64 rows x 128 cols. Wt is bf16 [n][k].
// BN_LOAD: y = relu(in*scale[k]+shift[k]) applied while staging A (fp32 math).
// STATS:   per-channel sum/sumsq of (acc+bias) via LDS -> global atomics.
// RELU_ST: relu on store. Output bf16.
template<bool BN_LOAD, bool STATS, bool RELU_ST>
__global__ __launch_bounds__(256)
void k_gemm(const unsigned short* __restrict__ In, unsigned short* __restrict__ Out,
            const unsigned short* __restrict__ Wt, const float* __restrict__ bias,
            const float* __restrict__ scale, const float* __restrict__ shift,
            float* __restrict__ stat_sum, float* __restrict__ stat_sq) {
    __shared__ __align__(16) unsigned short sA[64][136];   // +8 pad: bank-balanced b128
    __shared__ __align__(16) unsigned short sB[128][136];  // Wt[n][k] staged
    __shared__ float s_sum[128], s_sq[128];

    int t  = threadIdx.x;
    int r0 = blockIdx.x * 64;

    if (STATS && t < 128) { s_sum[t] = 0.f; s_sq[t] = 0.f; }

    // stage A: 64 rows x 16 chunks of 8 bf16
    #pragma unroll
    for (int u = 0; u < 4; ++u) {
        int f   = u * 256 + t;
        int row = f >> 4, kq = f & 15;
        int gr  = r0 + row;
        short8 v = {};
        if (gr < N_NODES) v = *(const short8*)(In + (size_t)gr * 128 + kq * 8);
        if (BN_LOAD) {
            #pragma unroll
            for (int j = 0; j < 8; ++j) {
                int k = kq * 8 + j;
                float fv = bf2f((unsigned short)v[j]);
                fv = fmaxf(fv * scale[k] + shift[k], 0.f);
                v[j] = (short)f2bf(fv);
            }
        }
        *(short8*)&sA[row][kq * 8] = v;
    }
    // stage B: 128 n-rows x 16 chunks of 8 bf16 (straight copy)
    #pragma unroll
    for (int u = 0; u < 8; ++u) {
        int f = u * 256 + t;
        int n = f >> 4, kq = f & 15;
        *(short8*)&sB[n][kq * 8] = *(const short8*)(Wt + n * 128 + kq * 8);
    }
    __syncthreads();

    int wave = t >> 6;
    int lane = t & 63;
    int m = lane & 15;       // col-in-tile / row-in-tile for A
    int q = lane >> 4;       // quad

    floatx4 acc[8] = {};
    #pragma unroll
    for (int kc = 0; kc < 128; kc += 32) {
        short8 a = *(const short8*)&sA[wave * 16 + m][kc + q * 8];
        #pragma unroll
        for (int c = 0; c < 8; ++c) {
            short8 b = *(const short8*)&sB[c * 16 + m][kc + q * 8];
            acc[c] = __builtin_amdgcn_mfma_f32_16x16x32_bf16(a, b, acc[c], 0, 0, 0);
        }
    }

    // epilogue: C[row = wave*16 + q*4 + r][col = c*16 + m]
    #pragma unroll
    for (int c = 0; c < 8; ++c) {
        int colg = c * 16 + m;
        float bv = bias[colg];
        float csum = 0.f, csq = 0.f;
        #pragma unroll
        for (int r = 0; r < 4; ++r) {
            int gr = r0 + wave * 16 + q * 4 + r;
            float v = acc[c][r] + bv;
            if (RELU_ST) v = fmaxf(v, 0.f);
            if (gr < N_NODES) {
                Out[(size_t)gr * 128 + colg] = f2bf(v);
                if (STATS) { csum += v; csq += v * v; }
            }
        }
        if (STATS) {
            atomicAdd(&s_sum[colg], csum);
            atomicAdd(&s_sq [colg], csq);
        }
    }
    if (STATS) {
        __syncthreads();
        if (t < 128) {
            atomicAdd(&stat_sum[t], s_sum[t]);
            atomicAdd(&stat_sq [t], s_sq[t]);
        }
    }
}

__global__ void k_bnfin(const float* __restrict__ sum, const float* __restrict__ sq,
                        const float* __restrict__ gamma, const float* __restrict__ beta,
                        float* __restrict__ scale, float* __restrict__ shift) {
    int c = threadIdx.x;
    if (c < DIM) {
        float m   = sum[c] * (1.0f / N_NODES);
        float var = sq[c] * (1.0f / N_NODES) - m * m;
        float inv = rsqrtf(var + BN_EPS);
        float sc  = gamma[c] * inv;
        scale[c] = sc;
        shift[c] = beta[c] - m * sc;
    }
}

// ============================ Pooling (batch sorted, bf16 in) ============================
#define POOL_BLOCKS 512
#define POOL_CHUNK  196
__global__ void k_pool(const unsigned short* __restrict__ h, const int* __restrict__ batch,
                       float* __restrict__ pooled) {
    int c  = threadIdx.x;                 // 128 threads = 128 channels
    int n0 = blockIdx.x * POOL_CHUNK;
    if (n0 >= N_NODES) return;
    int n1 = min(n0 + POOL_CHUNK, N_NODES);
    int g = batch[n0];
    float acc = 0.f;
    for (int i = n0; i < n1; ++i) {
        int gi = batch[i];
        if (gi != g) { atomicAdd(&pooled[g * DIM + c], acc); acc = 0.f; g = gi; }
        acc += bf2f(h[(size_t)i * DIM + c]);
    }
    atomicAdd(&pooled[g * DIM + c], acc);
}

// ============================ Readout (fp32, tiny) ============================
__global__ void k_readout1(const float* __restrict__ pooled, const float* __restrict__ W,
                           const float* __restrict__ b, float* __restrict__ r1) {
    int idx = blockIdx.x * 256 + threadIdx.x;      // 16384
    int g = idx >> 7, c = idx & 127;
    float s = b[c];
    const float* p = pooled + g * DIM;
    #pragma unroll 8
    for (int k = 0; k < DIM; ++k) s += p[k] * W[k * DIM + c];
    r1[idx] = fmaxf(s, 0.f);
}

__global__ void k_readout2(const float* __restrict__ r1, const float* __restrict__ W,
                           const float* __restrict__ b, float* __restrict__ out) {
    int idx = blockIdx.x * 256 + threadIdx.x;      // 1280
    if (idx >= NUM_GRAPHS * OUT_CH) return;
    int g = idx / OUT_CH, c = idx % OUT_CH;
    float s = b[c];
    const float* r = r1 + g * DIM;
    #pragma unroll 8
    for (int k = 0; k < DIM; ++k) s += r[k] * W[k * OUT_CH + c];
    out[idx] = s;
}

// ============================ Launch ============================
extern "C" void kernel_launch(void* const* d_in, const int* in_sizes, int n_in,
                              void* d_out, int out_size, void* d_ws, size_t ws_size,
                              hipStream_t stream) {
    const float* x   = (const float*)d_in[0];
    const int*   ei  = (const int*)d_in[1];
    const int*   bat = (const int*)d_in[2];
    const float* W1a = (const float*)d_in[3];
    const float* b1a = (const float*)d_in[4];
    const float* ga  = (const float*)d_in[5];
    const float* ba  = (const float*)d_in[6];
    const float* W2a = (const float*)d_in[7];
    const float* b2a = (const float*)d_in[8];
    const float* W1b = (const float*)d_in[9];
    const float* b1b = (const float*)d_in[10];
    const float* gb  = (const float*)d_in[11];
    const float* bbt = (const float*)d_in[12];
    const float* W2b = (const float*)d_in[13];
    const float* b2b = (const float*)d_in[14];
    const float* Wl1 = (const float*)d_in[15];
    const float* bl1 = (const float*)d_in[16];
    const float* Wl2 = (const float*)d_in[17];
    const float* bl2 = (const float*)d_in[18];
    float* out = (float*)d_out;

    const int* src = ei;
    const int* dst = ei + N_EDGES;

    char* w = (char*)d_ws;
    size_t off = 0;
    auto alloc = [&](size_t bytes) -> char* {
        char* p = w + off; off += (bytes + 255) & ~(size_t)255; return p;
    };
    unsigned short* xb   = (unsigned short*)alloc((size_t)N_NODES * DIM * 2);
    unsigned short* nb0  = (unsigned short*)alloc((size_t)N_NODES * DIM * 2);
    unsigned short* nb1  = (unsigned short*)alloc((size_t)N_NODES * DIM * 2);
    unsigned short* Wtb  = (unsigned short*)alloc((size_t)4 * DIM * DIM * 2);
    int*   row_ptr = (int*)  alloc((size_t)(N_NODES + 1) * 4);
    int*   cursor  = (int*)  alloc((size_t)N_NODES * 4);
    int*   col     = (int*)  alloc((size_t)N_EDGES * 4);
    int*   bsum    = (int*)  alloc(98 * 4);
    float* ssumA   = (float*)alloc(DIM * 4);
    float* ssqA    = (float*)alloc(DIM * 4);
    float* ssumB   = (float*)alloc(DIM * 4);
    float* ssqB    = (float*)alloc(DIM * 4);
    float* scale   = (float*)alloc(DIM * 4);
    float* shift   = (float*)alloc(DIM * 4);
    float* pooled  = (float*)alloc((size_t)NUM_GRAPHS * DIM * 4);
    float* r1      = (float*)alloc((size_t)NUM_GRAPHS * DIM * 4);

    hipMemsetAsync(cursor, 0, (size_t)N_NODES * 4, stream);
    hipMemsetAsync(ssumA,  0, DIM * 4 * 4, stream);   // ssumA/ssqA/ssumB/ssqB contiguous
    hipMemsetAsync(pooled, 0, (size_t)NUM_GRAPHS * DIM * 4, stream);

    // CSR build (by dst, col = src)
    k_count<<<N_EDGES / 256, 256, 0, stream>>>(dst, cursor);
    k_scanA<<<98, 256, 0, stream>>>(cursor, row_ptr, bsum);
    k_scanB<<<1, 64, 0, stream>>>(bsum, row_ptr);
    k_scanC<<<(N_NODES + 255) / 256, 256, 0, stream>>>(row_ptr, bsum, cursor);
    k_fill<<<N_EDGES / 256, 256, 0, stream>>>(src, dst, cursor, col);

    // dtype prep
    k_cvt_x<<<(N_NODES * DIM / 4) / 256, 256, 0, stream>>>(x, xb);
    k_prep_w<<<dim3(64, 4), 256, 0, stream>>>(W1a, W2a, W1b, W2b, Wtb);
    const unsigned short* Wt1a = Wtb;
    const unsigned short* Wt2a = Wtb + DIM * DIM;
    const unsigned short* Wt1b = Wtb + 2 * DIM * DIM;
    const unsigned short* Wt2b = Wtb + 3 * DIM * DIM;

    int agg_blocks  = (N_NODES * 64) / 256;
    int gemm_blocks = (N_NODES + 63) / 64;

    // conv1
    k_agg<<<agg_blocks, 256, 0, stream>>>(xb, nb0, row_ptr, col);
    k_gemm<false, true, false><<<gemm_blocks, 256, 0, stream>>>(nb0, nb1, Wt1a, b1a,
                                                                nullptr, nullptr, ssumA, ssqA);
    k_bnfin<<<1, 128, 0, stream>>>(ssumA, ssqA, ga, ba, scale, shift);
    k_gemm<true, false, true><<<gemm_blocks, 256, 0, stream>>>(nb1, nb0, Wt2a, b2a,
                                                               scale, shift, nullptr, nullptr);
    // conv2
    k_agg<<<agg_blocks, 256, 0, stream>>>(nb0, nb1, row_ptr, col);
    k_gemm<false, true, false><<<gemm_blocks, 256, 0, stream>>>(nb1, nb0, Wt1b, b1b,
                                                                nullptr, nullptr, ssumB, ssqB);
    k_bnfin<<<1, 128, 0, stream>>>(ssumB, ssqB, gb, bbt, scale, shift);
    k_gemm<true, false, true><<<gemm_blocks, 256, 0, stream>>>(nb0, nb1, Wt2b, b2b,
                                                               scale, shift, nullptr, nullptr);
    // readout
    k_pool<<<POOL_BLOCKS, 128, 0, stream>>>(nb1, bat, pooled);
    k_readout1<<<(NUM_GRAPHS * DIM) / 256, 256, 0, stream>>>(pooled, Wl1, bl1, r1);
    k_readout2<<<(NUM_GRAPHS * OUT_CH + 255) / 256, 256, 0, stream>>>(r1, Wl2, bl2, out);
}